// Round 3
// baseline (112.513 us; speedup 1.0000x reference)
//
#include <hip/hip_runtime.h>

// Problem constants (fixed by reference setup_inputs)
#define NTRAJ 8
#define NRES  500
#define NBINS 34
#define JT    256                  // j-tile per block
#define LDSROW 35                  // padded LDS row stride in dwords:
                                   // bank=(35j+b)%32, 35j%32=3j%32 bijective over j mod 32
                                   // -> 2 lanes/bank for wave64 = conflict-free (m136)
#define OUT_ELEMS (NTRAJ*NRES*3)   // 12000
#define OUT4 (OUT_ELEMS/4)         // 3000
#define RED_G 10
#define RED_PER (NRES/RED_G)       // 50 slabs per reduce group

// grid (NRES i, 2 j-tiles), block 256. Stage gw[i][j-tile][:] (34 KB contiguous)
// into LDS coalesced, then thread<->j computes all 8 trajectories from its LDS row.
// Partial slab layout [i][t][c][j] so epilogue stores are fully coalesced.
__global__ __launch_bounds__(256)
void force_main(const float* __restrict__ cb,    // [NTRAJ][NRES][3]
                const float* __restrict__ gw,    // [NRES i][NRES j][NBINS]
                const float* __restrict__ cen,   // [NBINS]
                const float* __restrict__ sig,   // [NBINS]
                float* __restrict__ part)        // [NRES i][NTRAJ][3][NRES j]
{
    __shared__ float sgw[JT * LDSROW];           // 35840 B -> 4 blocks/CU LDS-wise
    const int tid = threadIdx.x;
    const int i   = blockIdx.x;
    const int j0  = blockIdx.y * JT;
    const int nj  = min(JT, NRES - j0);          // 256 or 244

    // ---- stage: contiguous nj*34 floats, coalesced float2 loads ----
    const float2* gsrc = reinterpret_cast<const float2*>(
        gw + (size_t)i * (NRES * NBINS) + (size_t)j0 * NBINS);   // 8B-aligned
    const int nf2 = nj * (NBINS / 2);            // 4352 or 4148 float2s
    for (int f = tid; f < nf2; f += 256) {
        const float2 v = gsrc[f];
        const int jj = f / (NBINS / 2);          // /17 -> magic-mul
        const int bb = f - jj * (NBINS / 2);
        sgw[jj * LDSROW + 2 * bb + 0] = v.x;
        sgw[jj * LDSROW + 2 * bb + 1] = v.y;
    }
    __syncthreads();
    if (tid >= nj) return;                       // after the only barrier

    const int j = j0 + tid;

    // per-pair geometry, all trajectories (cb[t,i,:] wave-uniform -> s-loads)
    float dx[NTRAJ], dy[NTRAJ], dz[NTRAJ], d[NTRAJ];
#pragma unroll
    for (int t = 0; t < NTRAJ; ++t) {
        const float xi = cb[t * (NRES * 3) + i * 3 + 0];
        const float yi = cb[t * (NRES * 3) + i * 3 + 1];
        const float zi = cb[t * (NRES * 3) + i * 3 + 2];
        dx[t] = cb[t * (NRES * 3) + j * 3 + 0] - xi;   // cb[t,j] - cb[t,i]
        dy[t] = cb[t * (NRES * 3) + j * 3 + 1] - yi;
        dz[t] = cb[t * (NRES * 3) + j * 3 + 2] - zi;
        const float d2 = dx[t] * dx[t] + dy[t] * dy[t] + dz[t] * dz[t];
        d[t] = fminf(fmaxf(sqrtf(d2), 0.1f), 40.0f);   // clip(.,0.1,40)
    }

    float force[NTRAJ];
#pragma unroll
    for (int t = 0; t < NTRAJ; ++t) force[t] = 0.0f;

    const float* row = &sgw[tid * LDSROW];
#pragma unroll
    for (int k = 0; k < NBINS / 2; ++k) {
        const float w0 = row[2 * k + 0];         // ds_read2_b32, 2-way = free
        const float w1 = row[2 * k + 1];
#pragma unroll
        for (int u = 0; u < 2; ++u) {
            const int b   = 2 * k + u;
            const float w = u ? w1 : w0;
            const float sv = __builtin_amdgcn_rcpf(sig[b]);    // 1/sigma (uniform)
            const float s2 = sv * sv;
            const float c1 = s2 * -0.72134752044448f;          // -0.5*log2(e)/sig^2
            const float wb = (w * sv) * s2;                    // w/sigma^3 (per-lane)
            const float cc = cen[b];
#pragma unroll
            for (int t = 0; t < NTRAJ; ++t) {
                const float dfm = d[t] - cc;
                const float e   = __builtin_amdgcn_exp2f((dfm * c1) * dfm);
                force[t] = fmaf(-(dfm * wb), e, force[t]);
            }
        }
    }

    // epilogue: pair_accs = -force * K * diffs / d ; coalesced stores [t][c][j]
    float* p = part + (size_t)i * OUT_ELEMS;
#pragma unroll
    for (int t = 0; t < NTRAJ; ++t) {
        const float s = (force[t] * __builtin_amdgcn_rcpf(d[t])) * -150.0f;
        p[t * (3 * NRES) + 0 * NRES + j] = s * dx[t];
        p[t * (3 * NRES) + 1 * NRES + j] = s * dy[t];
        p[t * (3 * NRES) + 2 * NRES + j] = s * dz[t];
    }
}

// grid (12, RED_G), block 256. Sum one float4 over RED_PER slabs (coalesced),
// scatter-atomicAdd into out (10-way contention only; t,c constant per float4).
__global__ __launch_bounds__(256)
void reduce_k(const float* __restrict__ part, float* __restrict__ out)
{
    const int f = blockIdx.x * 256 + threadIdx.x;    // float4 idx over [t][c][j]
    if (f >= OUT4) return;
    const int g = blockIdx.y;

    const float4* p4 = reinterpret_cast<const float4*>(part);
    float4 s = make_float4(0.f, 0.f, 0.f, 0.f);
#pragma unroll 10
    for (int ic = g * RED_PER; ic < (g + 1) * RED_PER; ++ic) {
        const float4 v = p4[(size_t)ic * OUT4 + f];
        s.x += v.x; s.y += v.y; s.z += v.z; s.w += v.w;
    }
    // q = f*4 .. f*4+3 map to fixed (t,c), jj0..jj0+3 (500,1500 both %4==0)
    const int q0 = f * 4;
    const int t  = q0 / (3 * NRES);
    const int r  = q0 - t * (3 * NRES);
    const int c  = r / NRES;
    const int jj = r - c * NRES;
    float* o = out + t * (NRES * 3) + jj * 3 + c;
    atomicAdd(o + 0, s.x);
    atomicAdd(o + 3, s.y);
    atomicAdd(o + 6, s.z);
    atomicAdd(o + 9, s.w);
}

extern "C" void kernel_launch(void* const* d_in, const int* in_sizes, int n_in,
                              void* d_out, int out_size, void* d_ws, size_t ws_size,
                              hipStream_t stream)
{
    const float* cb  = (const float*)d_in[0];   // coords_cb [8,500,3]
    const float* gw  = (const float*)d_in[1];   // gaussian_weights [500,500,34]
    const float* cen = (const float*)d_in[2];   // dist_bin_centres [34]
    const float* sig = (const float*)d_in[3];   // sigmas [34]
    float* out  = (float*)d_out;                // [8,500,3]
    float* part = (float*)d_ws;                 // 500 * 12000 floats = 24 MB

    // zero the output (harness poisons it to 0xAA before every launch)
    hipMemsetAsync(out, 0, (size_t)OUT_ELEMS * sizeof(float), stream);

    force_main<<<dim3(NRES, 2), 256, 0, stream>>>(cb, gw, cen, sig, part);
    reduce_k<<<dim3((OUT4 + 255) / 256, RED_G), 256, 0, stream>>>(part, out);
}

// Round 4
// 103.873 us; speedup vs baseline: 1.0832x; 1.0832x over previous
//
#include <hip/hip_runtime.h>

// Problem constants (fixed by reference setup_inputs)
#define NTRAJ 8
#define NRES  500
#define NBINS 34
#define OUT_ELEMS (NTRAJ*NRES*3)   // 12000 floats per slab
#define SLAB4 (OUT_ELEMS/4)        // 3000 float4 per slab
#define RED_G 10                   // slab groups in reduce
#define RED_PER (NRES/RED_G)       // 50 slabs per group

// grid (NRES i, 2 j-tiles), block 256. thread -> one j; block -> one i.
// Direct per-thread float2 gw reads (R3 showed LDS staging is a net loss).
// Partial slab layout [i][c][j][t] (t innermost): epilogue = 6 coalesced
// float4 stores per thread (lane stride 32B).
__global__ __launch_bounds__(256)
void force_main(const float* __restrict__ cb,    // [NTRAJ][NRES][3]
                const float* __restrict__ gw,    // [NRES i][NRES j][NBINS]
                const float* __restrict__ cen,   // [NBINS]
                const float* __restrict__ sig,   // [NBINS]
                float* __restrict__ part)        // [NRES i][3][NRES j][NTRAJ]
{
    const int tid = threadIdx.x;
    const int j   = blockIdx.y * 256 + tid;
    const int i   = blockIdx.x;
    if (j >= NRES) return;   // 12 idle lanes in y=1 blocks; no barriers used

    // per-pair geometry, all trajectories (cb[t,i,:] wave-uniform -> s-loads)
    float dx[NTRAJ], dy[NTRAJ], dz[NTRAJ], d[NTRAJ];
#pragma unroll
    for (int t = 0; t < NTRAJ; ++t) {
        const float xi = cb[t * (NRES * 3) + i * 3 + 0];
        const float yi = cb[t * (NRES * 3) + i * 3 + 1];
        const float zi = cb[t * (NRES * 3) + i * 3 + 2];
        dx[t] = cb[t * (NRES * 3) + j * 3 + 0] - xi;   // cb[t,j] - cb[t,i]
        dy[t] = cb[t * (NRES * 3) + j * 3 + 1] - yi;
        dz[t] = cb[t * (NRES * 3) + j * 3 + 2] - zi;
        const float d2 = dx[t] * dx[t] + dy[t] * dy[t] + dz[t] * dz[t];
        d[t] = fminf(fmaxf(sqrtf(d2), 0.1f), 40.0f);   // clip(.,0.1,40)
    }

    float force[NTRAJ];
#pragma unroll
    for (int t = 0; t < NTRAJ; ++t) force[t] = 0.0f;

    // gw row for (i, j): 34 contiguous floats, 8B-aligned -> float2 loads.
    // 17 independent VMEM loads; latency hidden by ~16 waves/CU.
    const float2* g2 = reinterpret_cast<const float2*>(
        gw + (size_t)i * (NRES * NBINS) + (size_t)j * NBINS);

#pragma unroll
    for (int k = 0; k < NBINS / 2; ++k) {
        const float2 wpair = g2[k];
#pragma unroll
        for (int u = 0; u < 2; ++u) {
            const int b   = 2 * k + u;
            const float w = u ? wpair.y : wpair.x;
            // per-bin constants (compile-time b after unroll -> s_load + SALU)
            const float sv = __builtin_amdgcn_rcpf(sig[b]);    // 1/sigma
            const float s2 = sv * sv;                          // 1/sigma^2
            // exp(-0.5*(dfm/sig)^2) = exp2(dfm^2 * (-0.5*log2(e)/sig^2))
            const float c1 = s2 * -0.72134752044448f;
            const float wb = (w * sv) * s2;                    // w/sigma^3 (per-lane)
            const float cc = cen[b];
#pragma unroll
            for (int t = 0; t < NTRAJ; ++t) {
                const float dfm = d[t] - cc;
                const float e   = __builtin_amdgcn_exp2f((dfm * c1) * dfm);
                force[t] = fmaf(-(dfm * wb), e, force[t]);
            }
        }
    }

    // epilogue: pair_accs = -force * K * diffs / d
    float s[NTRAJ];
#pragma unroll
    for (int t = 0; t < NTRAJ; ++t)
        s[t] = (force[t] * __builtin_amdgcn_rcpf(d[t])) * -150.0f;

    float4* p4 = reinterpret_cast<float4*>(
        part + (size_t)i * OUT_ELEMS);           // [3][NRES][NTRAJ]
    {
        // c = 0 (x): 8 floats contiguous at ((0*NRES)+j)*NTRAJ
        const int base = j * (NTRAJ / 4);        // float4 index
        p4[0 * (NRES * 2) + base + 0] = make_float4(s[0]*dx[0], s[1]*dx[1], s[2]*dx[2], s[3]*dx[3]);
        p4[0 * (NRES * 2) + base + 1] = make_float4(s[4]*dx[4], s[5]*dx[5], s[6]*dx[6], s[7]*dx[7]);
        p4[1 * (NRES * 2) + base + 0] = make_float4(s[0]*dy[0], s[1]*dy[1], s[2]*dy[2], s[3]*dy[3]);
        p4[1 * (NRES * 2) + base + 1] = make_float4(s[4]*dy[4], s[5]*dy[5], s[6]*dy[6], s[7]*dy[7]);
        p4[2 * (NRES * 2) + base + 0] = make_float4(s[0]*dz[0], s[1]*dz[1], s[2]*dz[2], s[3]*dz[3]);
        p4[2 * (NRES * 2) + base + 1] = make_float4(s[4]*dz[4], s[5]*dz[5], s[6]*dz[6], s[7]*dz[7]);
    }
}

// grid (12, RED_G), block 256. Each thread sums one float4 (of the
// [c][j][t] slab space) across RED_PER slabs (coalesced), then 4 atomicAdds
// into out[t][j][c] (10-way contention only).
__global__ __launch_bounds__(256)
void reduce_k(const float* __restrict__ part, float* __restrict__ out)
{
    const int f = blockIdx.x * 256 + threadIdx.x;    // float4 idx in slab
    if (f >= SLAB4) return;
    const int g = blockIdx.y;

    const float4* p4 = reinterpret_cast<const float4*>(part);
    float4 s = make_float4(0.f, 0.f, 0.f, 0.f);
#pragma unroll 10
    for (int ic = g * RED_PER; ic < (g + 1) * RED_PER; ++ic) {
        const float4 v = p4[(size_t)ic * SLAB4 + f];
        s.x += v.x; s.y += v.y; s.z += v.z; s.w += v.w;
    }
    // q0 = f*4 in [c][j][t] space; t0 in {0,4}, (c,j) fixed across the 4
    const int q0 = f * 4;
    const int t0 = q0 & (NTRAJ - 1);
    const int jc = q0 >> 3;                // c*NRES + j
    const int c  = jc / NRES;
    const int j  = jc - c * NRES;
    float* o = out + t0 * (NRES * 3) + j * 3 + c;
    atomicAdd(o + 0 * (NRES * 3), s.x);
    atomicAdd(o + 1 * (NRES * 3), s.y);
    atomicAdd(o + 2 * (NRES * 3), s.z);
    atomicAdd(o + 3 * (NRES * 3), s.w);
}

extern "C" void kernel_launch(void* const* d_in, const int* in_sizes, int n_in,
                              void* d_out, int out_size, void* d_ws, size_t ws_size,
                              hipStream_t stream)
{
    const float* cb  = (const float*)d_in[0];   // coords_cb [8,500,3]
    const float* gw  = (const float*)d_in[1];   // gaussian_weights [500,500,34]
    const float* cen = (const float*)d_in[2];   // dist_bin_centres [34]
    const float* sig = (const float*)d_in[3];   // sigmas [34]
    float* out  = (float*)d_out;                // [8,500,3]
    float* part = (float*)d_ws;                 // 500 slabs * 12000 floats = 24 MB

    // zero the output (harness poisons it to 0xAA before every launch)
    hipMemsetAsync(out, 0, (size_t)OUT_ELEMS * sizeof(float), stream);

    force_main<<<dim3(NRES, 2), 256, 0, stream>>>(cb, gw, cen, sig, part);
    reduce_k<<<dim3((SLAB4 + 255) / 256, RED_G), 256, 0, stream>>>(part, out);
}

// Round 5
// 97.851 us; speedup vs baseline: 1.1498x; 1.0615x over previous
//
#include <hip/hip_runtime.h>

// Problem constants (fixed by reference setup_inputs)
#define NTRAJ 8
#define NRES  500
#define NBINS 34

// Single fused kernel. grid (NRES), block 256.
//   block  <-> j   (out[t,j,:] is a block-local sum over i)
//   thread <-> i   (i = tid and i = tid+256; tail 12 lanes idle on 2nd pass)
// Per-thread register accumulation acc[t][c], then wave shfl_xor butterfly
// + 4-wave LDS combine -> single writer per output float. No workspace,
// no atomics, no memset, one dispatch.
__global__ __launch_bounds__(256)
void force_all(const float* __restrict__ cb,    // [NTRAJ][NRES][3]
               const float* __restrict__ gw,    // [NRES i][NRES j][NBINS]
               const float* __restrict__ cen,   // [NBINS]
               const float* __restrict__ sig,   // [NBINS]
               float* __restrict__ out)         // [NTRAJ][NRES][3]
{
    const int tid = threadIdx.x;
    const int j   = blockIdx.x;

    // cb[t,j,:] is block-uniform -> scalar loads
    float xj[NTRAJ], yj[NTRAJ], zj[NTRAJ];
#pragma unroll
    for (int t = 0; t < NTRAJ; ++t) {
        xj[t] = cb[t * (NRES * 3) + j * 3 + 0];
        yj[t] = cb[t * (NRES * 3) + j * 3 + 1];
        zj[t] = cb[t * (NRES * 3) + j * 3 + 2];
    }

    float acc[NTRAJ][3];
#pragma unroll
    for (int t = 0; t < NTRAJ; ++t)
#pragma unroll
        for (int c = 0; c < 3; ++c)
            acc[t][c] = 0.0f;

#pragma unroll
    for (int ii = 0; ii < 2; ++ii) {
        const int i = ii * 256 + tid;
        if (i < NRES) {                          // divergence only in last wave of pass 2
            // geometry: diffs = cb[t,j] - cb[t,i]
            float dx[NTRAJ], dy[NTRAJ], dz[NTRAJ], d[NTRAJ];
#pragma unroll
            for (int t = 0; t < NTRAJ; ++t) {
                dx[t] = xj[t] - cb[t * (NRES * 3) + i * 3 + 0];
                dy[t] = yj[t] - cb[t * (NRES * 3) + i * 3 + 1];
                dz[t] = zj[t] - cb[t * (NRES * 3) + i * 3 + 2];
                const float d2 = dx[t] * dx[t] + dy[t] * dy[t] + dz[t] * dz[t];
                d[t] = fminf(fmaxf(sqrtf(d2), 0.1f), 40.0f);   // clip(.,0.1,40)
            }

            float force[NTRAJ];
#pragma unroll
            for (int t = 0; t < NTRAJ; ++t) force[t] = 0.0f;

            // gw row (i, j): 34 contiguous floats, 8B-aligned -> 17 float2 loads
            const float2* g2 = reinterpret_cast<const float2*>(
                gw + (size_t)i * (NRES * NBINS) + (size_t)j * NBINS);

#pragma unroll
            for (int k = 0; k < NBINS / 2; ++k) {
                const float2 wpair = g2[k];
#pragma unroll
                for (int u = 0; u < 2; ++u) {
                    const int b   = 2 * k + u;
                    const float w = u ? wpair.y : wpair.x;
                    // per-bin constants (b compile-time after unroll)
                    const float sv = __builtin_amdgcn_rcpf(sig[b]);   // 1/sigma
                    const float s2 = sv * sv;                         // 1/sigma^2
                    // exp(-0.5*(dfm/sig)^2) = exp2(dfm^2 * (-0.5*log2(e)/sig^2))
                    const float c1 = s2 * -0.72134752044448f;
                    const float wb = (w * sv) * s2;                   // w/sigma^3
                    const float cc = cen[b];
#pragma unroll
                    for (int t = 0; t < NTRAJ; ++t) {
                        const float dfm = d[t] - cc;
                        const float e   = __builtin_amdgcn_exp2f((dfm * c1) * dfm);
                        force[t] = fmaf(-(dfm * wb), e, force[t]);
                    }
                }
            }

            // pair_accs = -force * K * diffs / d ; accumulate into acc
#pragma unroll
            for (int t = 0; t < NTRAJ; ++t) {
                const float s = (force[t] * __builtin_amdgcn_rcpf(d[t])) * -150.0f;
                acc[t][0] = fmaf(s, dx[t], acc[t][0]);
                acc[t][1] = fmaf(s, dy[t], acc[t][1]);
                acc[t][2] = fmaf(s, dz[t], acc[t][2]);
            }
        }
    }

    // ---- block reduction: 64-lane shfl_xor butterfly, then 4-wave LDS combine
#pragma unroll
    for (int m = 1; m <= 32; m <<= 1)
#pragma unroll
        for (int t = 0; t < NTRAJ; ++t)
#pragma unroll
            for (int c = 0; c < 3; ++c)
                acc[t][c] += __shfl_xor(acc[t][c], m, 64);

    __shared__ float red[4][NTRAJ * 3];
    const int wv = tid >> 6;
    if ((tid & 63) == 0) {
#pragma unroll
        for (int t = 0; t < NTRAJ; ++t)
#pragma unroll
            for (int c = 0; c < 3; ++c)
                red[wv][t * 3 + c] = acc[t][c];
    }
    __syncthreads();
    if (tid < NTRAJ * 3) {
        const float s = red[0][tid] + red[1][tid] + red[2][tid] + red[3][tid];
        const int t = tid / 3;
        const int c = tid - t * 3;
        out[t * (NRES * 3) + j * 3 + c] = s;    // single writer per output
    }
}

extern "C" void kernel_launch(void* const* d_in, const int* in_sizes, int n_in,
                              void* d_out, int out_size, void* d_ws, size_t ws_size,
                              hipStream_t stream)
{
    const float* cb  = (const float*)d_in[0];   // coords_cb [8,500,3]
    const float* gw  = (const float*)d_in[1];   // gaussian_weights [500,500,34]
    const float* cen = (const float*)d_in[2];   // dist_bin_centres [34]
    const float* sig = (const float*)d_in[3];   // sigmas [34]
    float* out = (float*)d_out;                 // [8,500,3]

    force_all<<<dim3(NRES), 256, 0, stream>>>(cb, gw, cen, sig, out);
}